// Round 8
// baseline (360.075 us; speedup 1.0000x reference)
//
#include <hip/hip_runtime.h>
#include <hip/hip_fp16.h>

#define NB 2048
#define NC 8
#define NT 1024
#define EPS 1e-5f
#define SLOPE (1.0f/128.0f)
#define NELEM (2048.0f*1024.0f)
#define TB (NT*NB)

// ---- ws layout ----
// floats [0,1024)        : (unused scratch)
// floats [1024,1120)     : bn2 stat slots 11 o x 4 sub x 2 (sum,sumsq)
// floats [9216,10240)    : folded params (fp32 + packed-half2-as-uint), PAR block
// byte 65536             : xT  fp16 [T][B][8]   (32 MiB)
// byte 65536+32MiB       : pre fp16 [11][T][B]  (44 MiB planes)
// byte BN1P_BYTE         : bn1 per-block partials 2048 x 16 fp32 (128 KiB)
#define PAR_OFF 9216
// fp32 (index into par float array)
#define PF_S4  0
#define PF_O4  8
#define PF_B1F 16
#define PF_B2F 40
#define PF_B3F 56
// packed half2 (index into (unsigned*)par)
#define PU_A4   96
#define PU_W1   128
#define PU_W2   224
#define PU_W3X  416
#define PU_W3F  460
#define PU_W3L  504
#define PU_W3FF 548
#define NPAR    640
#define XT_BYTE  65536
#define PWS_BYTE (65536 + 2048*1024*8*2)
#define BN1P_BYTE (PWS_BYTE + 11*2048*1024*2)

typedef _Float16 h2 __attribute__((ext_vector_type(2)));
typedef __fp16  fp16v2 __attribute__((ext_vector_type(2)));
union U32H2 { unsigned u; h2 h; fp16v2 f; unsigned short us[2]; };
union XU { uint4 v; unsigned u[4]; unsigned short us[8]; };

__device__ __forceinline__ float leaky(float z){ return fmaxf(z, z*SLOPE); }
__device__ __forceinline__ unsigned short f2h(float v){ return __half_as_ushort(__float2half(v)); }
__device__ __forceinline__ float h2f(unsigned short u){ return __half2float(__ushort_as_half(u)); }
__device__ __forceinline__ h2 uph2(unsigned u){ U32H2 x; x.u = u; return x.h; }
__device__ __forceinline__ h2 pk(float a, float b){
    U32H2 x; x.f = __builtin_amdgcn_cvt_pkrtz(a, b); return x.h;
}
__device__ __forceinline__ unsigned pku(float a, float b){
    U32H2 x; x.f = __builtin_amdgcn_cvt_pkrtz(a, b); return x.u;
}

#if defined(__has_builtin)
#if __has_builtin(__builtin_amdgcn_fdot2)
#define HAVE_FDOT2 1
#endif
#endif
#ifdef HAVE_FDOT2
__device__ __forceinline__ float fdot2(h2 a, h2 b, float c){ return __builtin_amdgcn_fdot2(a, b, c, false); }
#else
__device__ __forceinline__ float fdot2(h2 a, h2 b, float c){
    return c + (float)a[0]*(float)b[0] + (float)a[1]*(float)b[1];
}
#endif

// ---------------- K0: BN1 partials + transpose x -> xT[t][b][8] fp16 ----------------
__global__ __launch_bounds__(256) void k0_tr(const float* __restrict__ x,
                                             unsigned short* __restrict__ xT,
                                             float* __restrict__ bn1p)
{
    __shared__ unsigned short tile[64*134];
    __shared__ float sred[4][4][2];
    const int tid = threadIdx.x;
    const int bg = blockIdx.x >> 4;
    const int tg = blockIdx.x & 15;
    const int b0 = bg*16, t0 = tg*64;
    float s = 0.f, s2 = 0.f;
#pragma unroll
    for(int r=0;r<8;r++){
        const int flat4 = r*256 + tid;
        const int row = flat4 >> 4;          // 0..127 = b*8+c
        const int t4  = flat4 & 15;
        const int b = row >> 3, c = row & 7;
        float4 v = *(const float4*)(x + (size_t)(b0+b)*8192 + c*1024 + t0 + t4*4);
        s  += v.x+v.y+v.z+v.w;
        s2 += v.x*v.x+v.y*v.y+v.z*v.z+v.w*v.w;
        const int base = b*8 + c;
        tile[(t4*4+0)*134 + base] = f2h(v.x);
        tile[(t4*4+1)*134 + base] = f2h(v.y);
        tile[(t4*4+2)*134 + base] = f2h(v.z);
        tile[(t4*4+3)*134 + base] = f2h(v.w);
    }
    // per-thread c is constant within 16-lane groups
#pragma unroll
    for(int m=8;m>=1;m>>=1){ s += __shfl_xor(s,m,64); s2 += __shfl_xor(s2,m,64); }
    const int lane = tid & 63, wave = tid >> 6;
    if((lane & 15) == 0){ sred[wave][lane>>4][0] = s; sred[wave][lane>>4][1] = s2; }
    __syncthreads();
    if(tid < 16){
        const int c = tid & 7, which = tid >> 3;
        const int w0 = (c < 4) ? 0 : 1, g = c & 3;
        const float v = sred[w0][g][which] + sred[w0+2][g][which];
        bn1p[(size_t)blockIdx.x*16 + which*8 + c] = v;   // distinct slot: no atomics, no memset
    }
#pragma unroll
    for(int r=0;r<8;r++){
        const int q = r*256 + tid;
        const int t = q >> 5, inner = q & 31;
        const unsigned int lo = *(const unsigned int*)&tile[t*134 + inner*4];
        const unsigned int hi = *(const unsigned int*)&tile[t*134 + inner*4 + 2];
        *(uint2*)(xT + ((size_t)(t0+t)*NB + b0)*8 + inner*4) = make_uint2(lo, hi);
    }
}

// ---------------- K2: finalize BN1, fold + pack weights, zero slots & out ----------------
__device__ __forceinline__ unsigned pk2u(float a, float b){
    U32H2 v; v.us[0] = f2h(a); v.us[1] = f2h(b); return v.u;
}
__global__ __launch_bounds__(256) void k2_fold(const float* __restrict__ g1, const float* __restrict__ bb1,
    const float* __restrict__ w1, const float* __restrict__ b1,
    const float* __restrict__ w2, const float* __restrict__ b2,
    const float* __restrict__ w3, const float* __restrict__ b3,
    const float* __restrict__ A, const float* __restrict__ bn1p,
    float* __restrict__ ws, float* __restrict__ out)
{
    float* par = ws + PAR_OFF;
    unsigned* paru = (unsigned*)par;
    __shared__ float red2[16][16];
    __shared__ float st[16];
    __shared__ float sc[8], oc[8];
    const int tid = threadIdx.x;
    // reduce 2048x16 bn1 partials: 16 groups x 16 counters, 128 slots each
    {
        const int c = tid & 15, grp = tid >> 4;
        float s = 0.f;
        for(int k=0;k<128;k++) s += bn1p[(size_t)(grp + 16*k)*16 + c];
        red2[grp][c] = s;
    }
    __syncthreads();
    if(tid < 16){
        float t = 0.f;
#pragma unroll
        for(int g=0;g<16;g++) t += red2[g][tid];
        st[tid] = t;
    }
    __syncthreads();
    if(tid<8){
        const float inv = 1.0f/NELEM;
        float m  = st[tid]*inv;
        float v  = st[8+tid]*inv - m*m;
        float s_ = g1[tid]*rsqrtf(v+EPS);
        float o_ = bb1[tid] - m*s_;
        sc[tid]=s_; oc[tid]=o_;
        par[PF_S4+tid]=4.f*s_; par[PF_O4+tid]=4.f*o_;
    }
    __syncthreads();
    if(tid<24){ float a=b1[tid]; for(int c=0;c<8;c++) a += w1[tid*8+c]*oc[c]; par[PF_B1F+tid]=a; }
    if(tid<16){ par[PF_B2F+tid]=b2[tid]; }
    if(tid<11){ float a=b3[tid]; for(int c=0;c<8;c++) a += w3[tid*48+8+c]*oc[c]; par[PF_B3F+tid]=a; }
    if(tid<96){ int o=tid>>2, j=tid&3;
        paru[PU_W1+tid] = pk2u(w1[o*8+2*j]*sc[2*j], w1[o*8+2*j+1]*sc[2*j+1]); }
    if(tid<192){ int o=tid/12, j=tid-o*12;
        paru[PU_W2+tid] = pk2u(w2[o*24+2*j], w2[o*24+2*j+1]); }
    if(tid<44){ int o=tid>>2, j=tid&3; int c0=2*j, c1=2*j+1;
        float xa = w3[o*48+c0] + w3[o*48+8+c0]*sc[c0];
        float xb = w3[o*48+c1] + w3[o*48+8+c1]*sc[c1];
        paru[PU_W3X+tid] = pk2u(xa, xb);
        paru[PU_W3F+tid] = pk2u(w3[o*48+32+c0], w3[o*48+32+c1]);
        paru[PU_W3L+tid] = pk2u(w3[o*48+40+c0], w3[o*48+40+c1]);
    }
    if(tid<88){ int o=tid>>3, j=tid&7;
        paru[PU_W3FF+tid] = pk2u(w3[o*48+16+2*j], w3[o*48+16+2*j+1]); }
    if(tid<32){ int i=tid>>2, j=tid&3;
        paru[PU_A4+tid] = pk2u(4.f*A[i*8+2*j], 4.f*A[i*8+2*j+1]); }
    // zero bn2 stat slots + d_out (replaces 2 memset nodes)
    if(tid<96) ws[1024+tid] = 0.f;
    for(int i=tid; i<2048*11; i+=256) out[i] = 0.f;
}

// ---------------- KMAIN: fused reservoir + FF + pre, P=4 position blocking ----------------
// grid: 8 bg(256 b) x 128 tg(8 t) = 1024 blocks, 4 waves/SIMD. Weights staged in LDS
// (wave-uniform ds_read = broadcast); A4/S4/O4 from const ws -> s_load/SGPR. Each weight
// word is fetched ONCE per 4 positions (r7 post-mortem: per-use weight fetch latency was
// the bottleneck). BN2 stats moved to k6s. Warm-up 24 (absmax-invariant, r6).
__global__ __launch_bounds__(256,4) void kmain(
    const unsigned short* __restrict__ xT,
    const float* __restrict__ ws, unsigned short* __restrict__ pws)
{
    __shared__ unsigned wl[NPAR];
    const float* par = ws + PAR_OFF;
    const unsigned* paru = (const unsigned*)par;
    const int tid = threadIdx.x;
    for(int i=tid; i<NPAR; i+=256) wl[i] = paru[i];
    __syncthreads();

    const int b  = (blockIdx.x >> 7)*256 + tid;
    const int tg = blockIdx.x & 127;
    const int t0 = tg*8;
    const int tw = (t0 >= 24) ? (t0 - 24) : 0;
    const unsigned* pa4 = paru + PU_A4;          // uniform const -> SGPR-hoistable

    h2 fh[4];
#pragma unroll
    for(int j=0;j<4;j++) fh[j] = pk(0.f, 0.f);

    // ---- warm-up: recurrence only ----
#pragma unroll 1
    for(int t=tw; t<t0; t++){
        XU ux; ux.v = *(const uint4*)(xT + ((size_t)t*NB + b)*8);
        float nf[8];
#pragma unroll
        for(int i=0;i<8;i++){
            float acc = fmaf(par[PF_S4+i], h2f(ux.us[i]), par[PF_O4+i]);
#pragma unroll
            for(int j=0;j<4;j++) acc = fdot2(uph2(pa4[i*4+j]), fh[j], acc);
            nf[i] = fminf(fmaxf(acc,-1.f),1.f);
        }
#pragma unroll
        for(int j=0;j<4;j++) fh[j] = pk(nf[2*j], nf[2*j+1]);
    }

    // ---- body: 2 groups of 4 positions ----
#pragma unroll 1
    for(int g=0; g<2; g++){
        const int tb = t0 + g*4;
        XU xw[4];
#pragma unroll
        for(int q=0;q<4;q++) xw[q].v = *(const uint4*)(xT + ((size_t)(tb+q)*NB + b)*8);

        h2 fhs[4][4], lfs[4][4];
#pragma unroll
        for(int q=0;q<4;q++){                    // serial recurrence over the 4 t's
            float nf[8];
#pragma unroll
            for(int i=0;i<8;i++){
                float acc = fmaf(par[PF_S4+i], h2f(xw[q].us[i]), par[PF_O4+i]);
#pragma unroll
                for(int j=0;j<4;j++) acc = fdot2(uph2(pa4[i*4+j]), fh[j], acc);
                nf[i] = fminf(fmaxf(acc,-1.f),1.f);
            }
#pragma unroll
            for(int j=0;j<4;j++){
                fh[j] = pk(nf[2*j], nf[2*j+1]);
                fhs[q][j] = fh[j];
                lfs[q][j] = pk(leaky(nf[2*j]), leaky(nf[2*j+1]));
            }
        }
        // ---- B': zpart = B3F + W3X·x + W3F·f + W3L·lf (then x/f/lf die) ----
        unsigned zp[22];
#pragma unroll
        for(int o=0;o<11;o++){
            float z[4];
#pragma unroll
            for(int q=0;q<4;q++){
                float zz = par[PF_B3F+o];
#pragma unroll
                for(int j=0;j<4;j++){
                    zz = fdot2(uph2(wl[PU_W3X+o*4+j]), uph2(xw[q].u[j]), zz);
                    zz = fdot2(uph2(wl[PU_W3F+o*4+j]), fhs[q][j], zz);
                    zz = fdot2(uph2(wl[PU_W3L+o*4+j]), lfs[q][j], zz);
                }
                z[q] = zz;
            }
            zp[o*2]   = pku(z[0], z[1]);
            zp[o*2+1] = pku(z[2], z[3]);
        }
        // ---- layer1: h = leaky(W1f·x + b1f), layer-major (weights x4 reuse) ----
        h2 hh[4][12];
#pragma unroll
        for(int p=0;p<12;p++){
#pragma unroll
            for(int q=0;q<4;q++){
                float za = par[PF_B1F+2*p], zb = par[PF_B1F+2*p+1];
#pragma unroll
                for(int j=0;j<4;j++){
                    za = fdot2(uph2(wl[PU_W1+(2*p)*4+j]),   uph2(xw[q].u[j]), za);
                    zb = fdot2(uph2(wl[PU_W1+(2*p+1)*4+j]), uph2(xw[q].u[j]), zb);
                }
                hh[q][p] = pk(leaky(za), leaky(zb));
            }
        }
        // ---- layer2: ff = leaky(W2·h + b2) ----
        h2 ffh[4][8];
#pragma unroll
        for(int p=0;p<8;p++){
#pragma unroll
            for(int q=0;q<4;q++){
                float za = par[PF_B2F+2*p], zb = par[PF_B2F+2*p+1];
#pragma unroll
                for(int j=0;j<12;j++){
                    za = fdot2(uph2(wl[PU_W2+(2*p)*12+j]),   hh[q][j], za);
                    zb = fdot2(uph2(wl[PU_W2+(2*p+1)*12+j]), hh[q][j], zb);
                }
                ffh[q][p] = pk(leaky(za), leaky(zb));
            }
        }
        // ---- layer3: z = zpart + W3FF·ff, store pre planes ----
#pragma unroll
        for(int o=0;o<11;o++){
#pragma unroll
            for(int q=0;q<4;q++){
                U32H2 zz; zz.u = zp[o*2+(q>>1)];
                float z = h2f(zz.us[q&1]);
#pragma unroll
                for(int j=0;j<8;j++) z = fdot2(uph2(wl[PU_W3FF+o*8+j]), ffh[q][j], z);
                pws[(size_t)o*TB + (size_t)(tb+q)*NB + b] = f2h(z);
            }
        }
    }
}

// ---------------- K6S: BN2 stats over pre planes ----------------
// grid: 11 o x 32 tg = 352 blocks; coalesced 2B/lane reads; 4 sub-slots (8 contenders).
__global__ __launch_bounds__(256) void k6s(const unsigned short* __restrict__ pws,
                                           float* __restrict__ ws)
{
    const int o = blockIdx.x >> 5, tg = blockIdx.x & 31;
    const int tid = threadIdx.x;
    float s = 0.f, s2 = 0.f;
    const unsigned short* pp = pws + (size_t)o*TB + tid;
#pragma unroll 1
    for(int i=0;i<32;i++){
        const size_t rowb = (size_t)(tg*32+i)*NB;
#pragma unroll
        for(int k=0;k<8;k++){
            float v = h2f(pp[rowb + k*256]);
            s += v; s2 += v*v;
        }
    }
#pragma unroll
    for(int m=32;m>=1;m>>=1){ s += __shfl_xor(s,m,64); s2 += __shfl_xor(s2,m,64); }
    __shared__ float red[4][2];
    const int wave = tid>>6, lane = tid&63;
    if(lane==0){ red[wave][0]=s; red[wave][1]=s2; }
    __syncthreads();
    if(tid==0){
        float ts = red[0][0]+red[1][0]+red[2][0]+red[3][0];
        float tq = red[0][1]+red[1][1]+red[2][1]+red[3][1];
        atomicAdd(&ws[1024 + (o*4+(tg&3))*2    ], ts);
        atomicAdd(&ws[1024 + (o*4+(tg&3))*2 + 1], tq);
    }
}

// ---------------- K6: BN2 finalize + apply + leaky + t-mean ----------------
// grid: 11 o x 8 bg x 8 tg = 704 blocks; atomicAdd into out (8 contenders/address).
__global__ __launch_bounds__(256) void k6(const float* __restrict__ ws,
                                          const unsigned short* __restrict__ pws,
                                          const float* __restrict__ g2, const float* __restrict__ bb2,
                                          float* __restrict__ out)
{
    const int o  = blockIdx.x >> 6;
    const int r  = blockIdx.x & 63;
    const int bg = r & 7, tg = r >> 3;
    const int tid = threadIdx.x;
    float sm = 0.f, sq = 0.f;
#pragma unroll
    for(int u=0;u<4;u++){ sm += ws[1024+(o*4+u)*2]; sq += ws[1024+(o*4+u)*2+1]; }
    const float inv = 1.0f/NELEM;
    const float m  = sm*inv;
    const float v  = sq*inv - m*m;
    const float al = g2[o]*rsqrtf(v+EPS);
    const float be = bb2[o] - m*al;
    const int b = bg*256 + tid;
    const unsigned short* pp = pws + (size_t)o*TB + b;
    float acc = 0.f;
#pragma unroll 4
    for(int i=0;i<128;i++){
        const int t = tg*128 + i;
        acc += leaky(fmaf(al, h2f(pp[(size_t)t*NB]), be));
    }
    atomicAdd(&out[b*11+o], acc*(1.0f/NT));
}

extern "C" void kernel_launch(void* const* d_in, const int* in_sizes, int n_in,
                              void* d_out, int out_size, void* d_ws, size_t ws_size,
                              hipStream_t stream)
{
    const float* x   = (const float*)d_in[0];
    const float* A   = (const float*)d_in[1];
    const float* g1  = (const float*)d_in[2];
    const float* bb1 = (const float*)d_in[3];
    const float* w1  = (const float*)d_in[4];
    const float* b1  = (const float*)d_in[5];
    const float* w2  = (const float*)d_in[6];
    const float* b2  = (const float*)d_in[7];
    const float* w3  = (const float*)d_in[8];
    const float* b3  = (const float*)d_in[9];
    const float* g2  = (const float*)d_in[10];
    const float* bb2 = (const float*)d_in[11];
    float* out = (float*)d_out;
    float* ws  = (float*)d_ws;
    unsigned short* xT   = (unsigned short*)((char*)d_ws + XT_BYTE);
    unsigned short* pws  = (unsigned short*)((char*)d_ws + PWS_BYTE);
    float*          bn1p = (float*)((char*)d_ws + BN1P_BYTE);

    k0_tr  <<<2048, 256, 0, stream>>>(x, xT, bn1p);
    k2_fold<<<1,    256, 0, stream>>>(g1, bb1, w1, b1, w2, b2, w3, b3, A, bn1p, ws, out);
    kmain  <<<1024, 256, 0, stream>>>(xT, ws, pws);
    k6s    <<<352,  256, 0, stream>>>(pws, ws);
    k6     <<<704,  256, 0, stream>>>(ws, pws, g2, bb2, out);
}